// Round 4
// baseline (145.515 us; speedup 1.0000x reference)
//
#include <hip/hip_runtime.h>

typedef unsigned short u16;
typedef unsigned long long u64;
typedef __bf16 bf16x8 __attribute__((ext_vector_type(8)));
typedef float f32x4 __attribute__((ext_vector_type(4)));

#define MFMA16(a, b, c) __builtin_amdgcn_mfma_f32_16x16x32_bf16((a), (b), (c), 0, 0, 0)

__device__ __forceinline__ bf16x8 ld8(const u16* p) {
    return *reinterpret_cast<const bf16x8*>(p);
}

__device__ __forceinline__ unsigned pk2(float a, float b) {
    unsigned short ua = __builtin_bit_cast(unsigned short, (__bf16)a);
    unsigned short ub = __builtin_bit_cast(unsigned short, (__bf16)b);
    return (unsigned)ua | ((unsigned)ub << 16);
}

__device__ __forceinline__ bf16x8 cvt8(float4 a, float4 b) {
    bf16x8 r;
    r[0] = (__bf16)a.x; r[1] = (__bf16)a.y; r[2] = (__bf16)a.z; r[3] = (__bf16)a.w;
    r[4] = (__bf16)b.x; r[5] = (__bf16)b.y; r[6] = (__bf16)b.z; r[7] = (__bf16)b.w;
    return r;
}

// ---- Kernel 0: mask bitpack (blocks 0..2047) + weight cvt (blocks 2048..2143) ----
// Bitpack: one wave per mask row. 16 int4 loads (1KB contiguous per instr, all in
// flight up-front), then converged ballots. Permuted layout:
//   bits[row][j=0..15][e=0..3] (u64): bit l = mask[row][256*j + 4*l + e]
__global__ __launch_bounds__(256) void packcvt_kernel(
    const int* __restrict__ mask, u64* __restrict__ bits,
    const float* __restrict__ Wq, const float* __restrict__ Wk,
    const float* __restrict__ Wv, u16* __restrict__ wb)
{
    if (blockIdx.x >= 2048) {
        const int t = (blockIdx.x - 2048) * 256 + threadIdx.x;
        const int mat = t >> 13;
        const int idx = (t & 8191) * 8;
        const float* src = (mat == 0) ? Wq : (mat == 1) ? Wk : Wv;
        float4 a = *(const float4*)(src + idx);
        float4 b = *(const float4*)(src + idx + 4);
        uint4 o;
        o.x = pk2(a.x, a.y); o.y = pk2(a.z, a.w);
        o.z = pk2(b.x, b.y); o.w = pk2(b.z, b.w);
        *reinterpret_cast<uint4*>(wb + (size_t)mat * 65536 + idx) = o;
        return;
    }

    const int lane = threadIdx.x & 63, w = threadIdx.x >> 6;
    const int row = blockIdx.x * 4 + w;                   // 0..8191
    const int* mp = mask + (size_t)row * 4096 + lane * 4;
    u64* op = bits + (size_t)row * 64;

    int4 h0[8], h1[8];                                    // 16 KB/wave in flight
    #pragma unroll
    for (int j = 0; j < 8; ++j) h0[j] = *(const int4*)(mp + j * 256);
    #pragma unroll
    for (int j = 0; j < 8; ++j) h1[j] = *(const int4*)(mp + 2048 + j * 256);

    u64 mine0 = 0, mine1 = 0;
    #pragma unroll
    for (int j = 0; j < 8; ++j) {
        // all ballots fully converged; per-lane keep is plain register select
        const u64 b0 = __ballot(h0[j].x != 0);
        const u64 b1 = __ballot(h0[j].y != 0);
        const u64 b2 = __ballot(h0[j].z != 0);
        const u64 b3 = __ballot(h0[j].w != 0);
        if (lane == j * 4 + 0) mine0 = b0;
        if (lane == j * 4 + 1) mine0 = b1;
        if (lane == j * 4 + 2) mine0 = b2;
        if (lane == j * 4 + 3) mine0 = b3;
        const u64 c0 = __ballot(h1[j].x != 0);
        const u64 c1 = __ballot(h1[j].y != 0);
        const u64 c2 = __ballot(h1[j].z != 0);
        const u64 c3 = __ballot(h1[j].w != 0);
        if (lane == j * 4 + 0) mine1 = c0;
        if (lane == j * 4 + 1) mine1 = c1;
        if (lane == j * 4 + 2) mine1 = c2;
        if (lane == j * 4 + 3) mine1 = c3;
    }
    if (lane < 32) { op[lane] = mine0; op[32 + lane] = mine1; }
}

// ---------------- Kernel 1: projections, depth-8 register-prefetched ----------------
__global__ __launch_bounds__(256, 1) void proj_kernel(
    const float* __restrict__ Q, const float* __restrict__ K, const float* __restrict__ V,
    const float* __restrict__ bq, const float* __restrict__ bk, const float* __restrict__ bv,
    const u16* __restrict__ wb, u16* __restrict__ qb, u16* __restrict__ kb,
    u16* __restrict__ vtb)
{
    const int mat  = blockIdx.x >> 7;
    const int tile = blockIdx.x & 127;
    const int lane = threadIdx.x & 63;
    const int w    = threadIdx.x >> 6;
    const int c = lane & 15, g = lane >> 4;

    const float* X = (mat == 0) ? Q : (mat == 1) ? K : V;
    const u16*   W = wb + (size_t)mat * 65536;

    const int rw = tile * 64 + w * 16;
    const float* xp = X + (size_t)(rw + c) * 1024 + g * 8;
    const u16*   wp = W + (size_t)c * 1024 + g * 8;

    f32x4 acc[4] = {};

    float4 A[8], B[8];                                   // depth-8 ring, 16 KB/wave in flight
    #pragma unroll
    for (int j = 0; j < 8; ++j) {
        A[j] = *(const float4*)(xp + j * 32);
        B[j] = *(const float4*)(xp + j * 32 + 4);
    }

    #pragma unroll 1
    for (int kt = 0; kt < 4; ++kt) {
        const int base  = kt * 8;
        const int nbase = (kt < 3) ? base + 8 : base;    // tail: clamped reload (harmless)
        #pragma unroll
        for (int j = 0; j < 8; ++j) {                    // fully unrolled -> static A/B idx
            const bf16x8 a = cvt8(A[j], B[j]);
            A[j] = *(const float4*)(xp + (nbase + j) * 32);
            B[j] = *(const float4*)(xp + (nbase + j) * 32 + 4);
            const u16* wk = wp + (base + j) * 32;
            if (mat < 2) {
                #pragma unroll
                for (int t = 0; t < 4; ++t)
                    acc[t] = MFMA16(a, ld8(wk + t * 16384), acc[t]);
            } else {
                #pragma unroll
                for (int t = 0; t < 4; ++t)
                    acc[t] = MFMA16(ld8(wk + t * 16384), a, acc[t]);
            }
        }
    }

    if (mat < 2) {
        const float* bias = (mat == 0) ? bq : bk;
        u16* dst = (mat == 0) ? qb : kb;
        #pragma unroll
        for (int t = 0; t < 4; ++t) {
            const float bz = bias[t * 16 + c];
            #pragma unroll
            for (int r = 0; r < 4; ++r) {
                const int row = rw + g * 4 + r;
                dst[(size_t)row * 64 + t * 16 + c] =
                    __builtin_bit_cast(u16, (__bf16)(acc[t][r] + bz));
            }
        }
    } else {
        const int sg = rw + c;
        const int bidx = sg >> 12, sin = sg & 4095;
        #pragma unroll
        for (int t = 0; t < 4; ++t) {
            #pragma unroll
            for (int r = 0; r < 4; ++r) {
                const int dv = t * 16 + g * 4 + r;
                vtb[(size_t)(bidx * 64 + dv) * 4096 + sin] =
                    __builtin_bit_cast(u16, (__bf16)(acc[t][r] + bv[dv]));
            }
        }
    }
}

// ---------------- Kernel 2: flash attention phase 1 (mask words hoisted to regs) ----
__global__ __launch_bounds__(256) void attn_kernel(
    const u64* __restrict__ bits, const u16* __restrict__ qb,
    const u16* __restrict__ kb, const u16* __restrict__ vtb,
    float* __restrict__ pacc, float* __restrict__ pm, float* __restrict__ pl)
{
    __shared__ uint2 plds[4][128];   // per-wave 16q x 32s bf16, XOR-swizzled
    const int lane = threadIdx.x & 63, w = threadIdx.x >> 6;
    const int c = lane & 15, g = lane >> 4;
    const int gw    = blockIdx.x * 4 + w;
    const int strip = gw >> 3;
    const int chunk = gw & 7;
    const int b     = strip >> 8;
    const int q0    = (strip & 255) * 16;
    const int sBase = chunk * 512;
    const float SSC = 0.18033688011112042f;   // (1/8) * log2(e)

    const u16* qrow = qb + (size_t)((b << 12) + q0 + c) * 64 + g * 8;
    const bf16x8 qf0 = ld8(qrow);
    const bf16x8 qf1 = ld8(qrow + 32);

    const u16* kfp = kb  + (((size_t)b << 12) + sBase + c) * 64 + g * 8;
    const u16* vfp = vtb + (size_t)(b * 64 + c) * 4096 + sBase + g * 8;

    // hoist ALL mask words for this (q-row, s-chunk): windows 2*chunk, 2*chunk+1
    // bit l of Wrd[sel*4+e] = mask[row][chunk*512 + sel*256 + 4*l + e]
    const u64* bp = bits + (size_t)((b << 12) + q0 + c) * 64 + chunk * 8;
    const u64 Wd0 = bp[0], Wd1 = bp[1], Wd2 = bp[2], Wd3 = bp[3];
    const u64 Wd4 = bp[4], Wd5 = bp[5], Wd6 = bp[6], Wd7 = bp[7];

    f32x4 acc0 = {}, acc1 = {}, acc2 = {}, acc3 = {};
    const f32x4 zf = {};
    float m_run = -__builtin_inff(), l_run = 0.f;

    // K frags double-buffered one iter ahead
    bf16x8 k00 = ld8(kfp),            k01 = ld8(kfp + 32);
    bf16x8 k10 = ld8(kfp + 16 * 64),  k11 = ld8(kfp + 16 * 64 + 32);

    #pragma unroll
    for (int half = 0; half < 2; ++half) {               // compile-time word select
        const u64 Wr0 = half ? Wd4 : Wd0;
        const u64 Wr1 = half ? Wd5 : Wd1;
        const u64 Wr2 = half ? Wd6 : Wd2;
        const u64 Wr3 = half ? Wd7 : Wd3;
        #pragma unroll 1
        for (int it2 = 0; it2 < 8; ++it2) {
            const int it = half * 8 + it2;
            const int s0 = sBase + it * 32;

            // V frags for THIS iter: issued early, consumed after softmax
            const u16* vp = vfp + it * 32;
            const bf16x8 v0 = ld8(vp);
            const bf16x8 v1 = ld8(vp + 16 * 4096);
            const bf16x8 v2 = ld8(vp + 32 * 4096);
            const bf16x8 v3 = ld8(vp + 48 * 4096);

            // QK^T swapped (D[s][q]) with prefetched K regs
            f32x4 d0 = MFMA16(k00, qf0, zf);
            d0 = MFMA16(k01, qf1, d0);
            f32x4 d1 = MFMA16(k10, qf0, zf);
            d1 = MFMA16(k11, qf1, d1);

            // prefetch next iter's K frags
            const int no = (it < 15) ? (it + 1) * 2048 : it * 2048;
            k00 = ld8(kfp + no);            k01 = ld8(kfp + no + 32);
            k10 = ld8(kfp + no + 16 * 64);  k11 = ld8(kfp + no + 16 * 64 + 32);

            // mask bits from hoisted words: bit (it2*8 + 4h + g) of Wr[r]
            const int sh = it2 * 8 + g;
            const unsigned t0 = (unsigned)(Wr0 >> sh);
            const unsigned t1 = (unsigned)(Wr1 >> sh);
            const unsigned t2 = (unsigned)(Wr2 >> sh);
            const unsigned t3 = (unsigned)(Wr3 >> sh);

            const float x0 = (t0 & 1u)  ? d0[0] * SSC : -1e9f;
            const float x1 = (t1 & 1u)  ? d0[1] * SSC : -1e9f;
            const float x2 = (t2 & 1u)  ? d0[2] * SSC : -1e9f;
            const float x3 = (t3 & 1u)  ? d0[3] * SSC : -1e9f;
            const float x4 = (t0 & 16u) ? d1[0] * SSC : -1e9f;
            const float x5 = (t1 & 16u) ? d1[1] * SSC : -1e9f;
            const float x6 = (t2 & 16u) ? d1[2] * SSC : -1e9f;
            const float x7 = (t3 & 16u) ? d1[3] * SSC : -1e9f;

            float tm = fmaxf(fmaxf(fmaxf(x0, x1), fmaxf(x2, x3)),
                             fmaxf(fmaxf(x4, x5), fmaxf(x6, x7)));
            tm = fmaxf(tm, __shfl_xor(tm, 16));
            tm = fmaxf(tm, __shfl_xor(tm, 32));
            const float m_new = fmaxf(m_run, tm);
            const float f = exp2f(m_run - m_new);

            const float p0 = exp2f(x0 - m_new), p1 = exp2f(x1 - m_new);
            const float p2 = exp2f(x2 - m_new), p3 = exp2f(x3 - m_new);
            const float p4 = exp2f(x4 - m_new), p5 = exp2f(x5 - m_new);
            const float p6 = exp2f(x6 - m_new), p7 = exp2f(x7 - m_new);
            float rs = ((p0 + p1) + (p2 + p3)) + ((p4 + p5) + (p6 + p7));
            rs += __shfl_xor(rs, 16);
            rs += __shfl_xor(rs, 32);
            l_run = l_run * f + rs;
            m_run = m_new;

            // P -> LDS (row q=c), 8B chunks XOR-swizzled by (q&7)
            plds[w][c * 8 + ( g      ^ (c & 7))] = make_uint2(pk2(p0, p1), pk2(p2, p3));
            plds[w][c * 8 + ((g + 4) ^ (c & 7))] = make_uint2(pk2(p4, p5), pk2(p6, p7));

            if (__any(f < 1.0f)) {                     // rescale (rare after warm-up)
                const float f0 = __shfl(f, g * 4 + 0);
                const float f1 = __shfl(f, g * 4 + 1);
                const float f2 = __shfl(f, g * 4 + 2);
                const float f3 = __shfl(f, g * 4 + 3);
                acc0[0] *= f0; acc0[1] *= f1; acc0[2] *= f2; acc0[3] *= f3;
                acc1[0] *= f0; acc1[1] *= f1; acc1[2] *= f2; acc1[3] *= f3;
                acc2[0] *= f0; acc2[1] *= f1; acc2[2] *= f2; acc2[3] *= f3;
                acc3[0] *= f0; acc3[1] *= f1; acc3[2] *= f2; acc3[3] *= f3;
            }

            // PV: A = P[q=c][s-run g*8..+7] from LDS, B = vT frags in regs
            union { uint2 u[2]; bf16x8 v; } pa;
            pa.u[0] = plds[w][c * 8 + ((2 * g    ) ^ (c & 7))];
            pa.u[1] = plds[w][c * 8 + ((2 * g + 1) ^ (c & 7))];

            acc0 = MFMA16(pa.v, v0, acc0);
            acc1 = MFMA16(pa.v, v1, acc1);
            acc2 = MFMA16(pa.v, v2, acc2);
            acc3 = MFMA16(pa.v, v3, acc3);
        }
    }

    const size_t pidx = (size_t)(strip * 8 + chunk) * 16;
    #pragma unroll
    for (int r = 0; r < 4; ++r) {
        const size_t row = pidx + g * 4 + r;
        pacc[row * 64 +  0 + c] = acc0[r];
        pacc[row * 64 + 16 + c] = acc1[r];
        pacc[row * 64 + 32 + c] = acc2[r];
        pacc[row * 64 + 48 + c] = acc3[r];
    }
    if (lane < 16) {
        pm[pidx + c] = m_run;
        pl[pidx + c] = l_run;
    }
}

// ---------------- Kernel 3: combine 8 s-chunk partials per row ----------------
__global__ __launch_bounds__(256) void comb_kernel(
    const float* __restrict__ pacc, const float* __restrict__ pm,
    const float* __restrict__ pl, float* __restrict__ out)
{
    const int t = blockIdx.x * 256 + threadIdx.x;
    const int r = t >> 6, dv = t & 63;
    const int strip = r >> 4, qi = r & 15;
    const int base = strip * 128 + qi;
    float mv[8];
    float M = -__builtin_inff();
    #pragma unroll
    for (int cc = 0; cc < 8; ++cc) { mv[cc] = pm[base + cc * 16]; M = fmaxf(M, mv[cc]); }
    float num = 0.f, den = 0.f;
    #pragma unroll
    for (int cc = 0; cc < 8; ++cc) {
        const float wgt = exp2f(mv[cc] - M);
        num += wgt * pacc[(size_t)(base + cc * 16) * 64 + dv];
        den += wgt * pl[base + cc * 16];
    }
    out[t] = num / den;
}

extern "C" void kernel_launch(void* const* d_in, const int* in_sizes, int n_in,
                              void* d_out, int out_size, void* d_ws, size_t ws_size,
                              hipStream_t stream)
{
    const float* Q    = (const float*)d_in[0];
    const float* K    = (const float*)d_in[1];
    const float* V    = (const float*)d_in[2];
    const int*   mask = (const int*)d_in[3];
    const float* Wq   = (const float*)d_in[4];
    const float* bq   = (const float*)d_in[5];
    const float* Wk   = (const float*)d_in[6];
    const float* bk   = (const float*)d_in[7];
    const float* Wv   = (const float*)d_in[8];
    const float* bv   = (const float*)d_in[9];
    float* out = (float*)d_out;

    char* ws = (char*)d_ws;
    u16*   wb   = (u16*)(ws);                            // 384 KB
    u16*   qb   = (u16*)(ws + 393216);                   // 1 MB
    u16*   kb   = (u16*)(ws + 393216 + 1048576);         // 1 MB
    u16*   vtb  = (u16*)(ws + 393216 + 2097152);         // 1 MB
    u64*   bits = (u64*)(ws + 4194304);                  // 4 MB: [8192][16][4] u64
    float* pm   = (float*)(ws + 8388608);                // 256 KB
    float* pl   = (float*)(ws + 8388608 + 262144);       // 256 KB
    float* pacc = (float*)(ws + 8388608 + 524288);       // 16 MB

    packcvt_kernel<<<2144, 256, 0, stream>>>(mask, bits, Wq, Wk, Wv, wb);
    proj_kernel<<<384, 256, 0, stream>>>(Q, K, V, bq, bk, bv, wb, qb, kb, vtb);
    attn_kernel<<<1024, 256, 0, stream>>>(bits, qb, kb, vtb, pacc, pm, pl);
    comb_kernel<<<2048, 256, 0, stream>>>(pacc, pm, pl, out);
}

// Round 5
// 127.143 us; speedup vs baseline: 1.1445x; 1.1445x over previous
//
#include <hip/hip_runtime.h>

typedef unsigned short u16;
typedef unsigned long long u64;
typedef __bf16 bf16x8 __attribute__((ext_vector_type(8)));
typedef float f32x4 __attribute__((ext_vector_type(4)));

#define MFMA16(a, b, c) __builtin_amdgcn_mfma_f32_16x16x32_bf16((a), (b), (c), 0, 0, 0)
#define WAITVM(N) asm volatile("s_waitcnt vmcnt(" #N ")" ::: "memory")

// Async global->LDS, 16B per lane, dest = wave-uniform base + lane*16.
// Side-effecting intrinsic: issues at the program point it's written (the
// compiler cannot sink it), completion tracked by vmcnt.
__device__ __forceinline__ void gld16(const void* g, void* l) {
    __builtin_amdgcn_global_load_lds(
        (const __attribute__((address_space(1))) void*)g,
        (__attribute__((address_space(3))) void*)l, 16, 0, 0);
}

__device__ __forceinline__ bf16x8 ld8(const u16* p) {
    return *reinterpret_cast<const bf16x8*>(p);
}

__device__ __forceinline__ unsigned pk2(float a, float b) {
    unsigned short ua = __builtin_bit_cast(unsigned short, (__bf16)a);
    unsigned short ub = __builtin_bit_cast(unsigned short, (__bf16)b);
    return (unsigned)ua | ((unsigned)ub << 16);
}

__device__ __forceinline__ bf16x8 cvt8(float4 a, float4 b) {
    bf16x8 r;
    r[0] = (__bf16)a.x; r[1] = (__bf16)a.y; r[2] = (__bf16)a.z; r[3] = (__bf16)a.w;
    r[4] = (__bf16)b.x; r[5] = (__bf16)b.y; r[6] = (__bf16)b.z; r[7] = (__bf16)b.w;
    return r;
}

// ---------------- Kernel 0: convert Wq/Wk/Wv fp32 -> bf16 ----------------
// Separate dispatch: fused_kernel's proj path READS wb (same-dispatch = race).
__global__ __launch_bounds__(256) void wcvt_kernel(
    const float* __restrict__ Wq, const float* __restrict__ Wk,
    const float* __restrict__ Wv, u16* __restrict__ wb)
{
    const int t = blockIdx.x * 256 + threadIdx.x;
    const int mat = t >> 13;
    const int idx = (t & 8191) * 8;
    const float* src = (mat == 0) ? Wq : (mat == 1) ? Wk : Wv;
    float4 a = *(const float4*)(src + idx);
    float4 b = *(const float4*)(src + idx + 4);
    uint4 o;
    o.x = pk2(a.x, a.y); o.y = pk2(a.z, a.w);
    o.z = pk2(b.x, b.y); o.w = pk2(b.z, b.w);
    *reinterpret_cast<uint4*>(wb + (size_t)mat * 65536 + idx) = o;
}

// ---- Kernel 1: FUSED proj (blocks 0..383) + mask bitpack (blocks 384..4479) ----
// Both paths: per-wave PRIVATE 3-slot LDS ring fed by global_load_lds (width 16),
// counted s_waitcnt vmcnt(N) (never 0 mid-loop), no __syncthreads anywhere.
__global__ __launch_bounds__(256) void fused_kernel(
    const float* __restrict__ Q, const float* __restrict__ K, const float* __restrict__ V,
    const float* __restrict__ bq, const float* __restrict__ bk, const float* __restrict__ bv,
    const u16* __restrict__ wb, const int* __restrict__ mask,
    u16* __restrict__ qb, u16* __restrict__ kb, u16* __restrict__ vtb,
    u64* __restrict__ bits)
{
    __shared__ float ldsf[4][3][512];     // 24 KB: [wave][slot][2KB stage]
    const int lane = threadIdx.x & 63, w = threadIdx.x >> 6;

    if (blockIdx.x >= 384) {
        // ======== mask bitpack: wave = half mask row (2048 ints = 8KB) ========
        const int gwv = (blockIdx.x - 384) * 4 + w;         // 0..16383
        const int row = gwv >> 1, h = gwv & 1;
        const int* mp = mask + (size_t)row * 4096 + h * 2048 + lane * 4;
        int* ldsw = (int*)&ldsf[w][0][0];

        // prologue: stages 0,1 -> slots 0,1 (2 gld16 each, 1KB per instr)
        gld16(mp +    0, ldsw +    0);
        gld16(mp +  256, ldsw +  256);
        gld16(mp +  512, ldsw +  512);
        gld16(mp +  768, ldsw +  768);

        u64 mine = 0;
        #pragma unroll
        for (int st = 0; st < 4; ++st) {
            const int slot = st % 3;                         // compile-time (unrolled)
            if (st < 2) {                                    // stage st+2 -> slot (st+2)%3
                gld16(mp + (st + 2) * 512,       ldsw + ((st + 2) % 3) * 512);
                gld16(mp + (st + 2) * 512 + 256, ldsw + ((st + 2) % 3) * 512 + 256);
            }
            if (st < 2)       { WAITVM(4); }                 // leave next stages in flight
            else if (st == 2) { WAITVM(2); }
            else              { WAITVM(0); }
            #pragma unroll
            for (int wdw = 0; wdw < 2; ++wdw) {
                // lane-linear int4 LDS read (2-way banks = free), converged ballots
                const int4 m4 = *(const int4*)(ldsw + slot * 512 + wdw * 256 + lane * 4);
                const u64 b0 = __ballot(m4.x != 0);
                const u64 b1 = __ballot(m4.y != 0);
                const u64 b2 = __ballot(m4.z != 0);
                const u64 b3 = __ballot(m4.w != 0);
                const int base = (st * 2 + wdw) * 4;
                if (lane == base + 0) mine = b0;
                if (lane == base + 1) mine = b1;
                if (lane == base + 2) mine = b2;
                if (lane == base + 3) mine = b3;
            }
        }
        // layout: bits[row][j=0..15][e=0..3], bit l = mask[row][256j + 4l + e]
        if (lane < 32) bits[(size_t)row * 64 + h * 32 + lane] = mine;
        return;
    }

    // ======== projections: wave = 16 rows, 32-col fp32 stages via LDS ring ========
    const int mat  = blockIdx.x >> 7;
    const int tile = blockIdx.x & 127;
    const int c = lane & 15, g = lane >> 4;

    const float* X = (mat == 0) ? Q : (mat == 1) ? K : V;
    const u16*   W = wb + (size_t)mat * 65536;
    const int rw = tile * 64 + w * 16;

    // staging source (pre-swizzled granules so LDS stays linear, reads conflict-free):
    // instr j, lane i -> row rw + j*8 + (i>>3), col granule (i&7)^((i>>3)&7) of stage
    const int srow = lane >> 3;
    const int sgr  = (lane & 7) ^ srow;
    const float* s0p = X + (size_t)(rw + srow) * 1024 + sgr * 4;
    const float* s1p = s0p + 8 * 1024;
    float* ldsw = &ldsf[w][0][0];

    // consume-side swizzled granule addresses for this thread (row c, cols g*8..+7)
    const int G1 = c * 8 + ((2 * g)     ^ (c & 7));
    const int G2 = c * 8 + ((2 * g + 1) ^ (c & 7));

    const u16* wp = W + (size_t)c * 1024 + g * 8;
    f32x4 acc[4] = {};

    // prologue: stages 0,1 (stage t = cols t*32..t*32+31)
    gld16(s0p +  0, ldsw +    0);
    gld16(s1p +  0, ldsw +  256);
    gld16(s0p + 32, ldsw +  512);
    gld16(s1p + 32, ldsw +  768);

    int slot = 0;
    #pragma unroll 1
    for (int kk = 0; kk < 32; ++kk) {
        if (kk < 30) {                                       // stage kk+2 -> slot (kk+2)%3
            const int ns = (slot == 0) ? 2 : slot - 1;       // (kk+2)%3
            gld16(s0p + (kk + 2) * 32, ldsw + ns * 512);
            gld16(s1p + (kk + 2) * 32, ldsw + ns * 512 + 256);
        }
        if (kk < 30)       { WAITVM(4); }                    // stage kk ready, 2 in flight
        else if (kk == 30) { WAITVM(2); }
        else               { WAITVM(0); }

        const float4 xa = *(const float4*)(ldsw + slot * 512 + G1 * 4);
        const float4 xb = *(const float4*)(ldsw + slot * 512 + G2 * 4);
        const bf16x8 a = cvt8(xa, xb);

        const u16* wk = wp + kk * 32;
        if (mat < 2) {
            #pragma unroll
            for (int t = 0; t < 4; ++t)
                acc[t] = MFMA16(a, ld8(wk + t * 16384), acc[t]);
        } else {
            #pragma unroll
            for (int t = 0; t < 4; ++t)
                acc[t] = MFMA16(ld8(wk + t * 16384), a, acc[t]);
        }
        slot = (slot == 2) ? 0 : slot + 1;
    }

    if (mat < 2) {
        const float* bias = (mat == 0) ? bq : bk;
        u16* dst = (mat == 0) ? qb : kb;
        #pragma unroll
        for (int t = 0; t < 4; ++t) {
            const float bz = bias[t * 16 + c];
            #pragma unroll
            for (int r = 0; r < 4; ++r) {
                const int row = rw + g * 4 + r;
                dst[(size_t)row * 64 + t * 16 + c] =
                    __builtin_bit_cast(u16, (__bf16)(acc[t][r] + bz));
            }
        }
    } else {
        const int sg = rw + c;
        const int bidx = sg >> 12, sin = sg & 4095;
        #pragma unroll
        for (int t = 0; t < 4; ++t) {
            #pragma unroll
            for (int r = 0; r < 4; ++r) {
                const int dv = t * 16 + g * 4 + r;
                vtb[(size_t)(bidx * 64 + dv) * 4096 + sin] =
                    __builtin_bit_cast(u16, (__bf16)(acc[t][r] + bv[dv]));
            }
        }
    }
}

// ---------------- Kernel 2: flash attention phase 1 (unchanged from R4) ----------------
__global__ __launch_bounds__(256) void attn_kernel(
    const u64* __restrict__ bits, const u16* __restrict__ qb,
    const u16* __restrict__ kb, const u16* __restrict__ vtb,
    float* __restrict__ pacc, float* __restrict__ pm, float* __restrict__ pl)
{
    __shared__ uint2 plds[4][128];   // per-wave 16q x 32s bf16, XOR-swizzled
    const int lane = threadIdx.x & 63, w = threadIdx.x >> 6;
    const int c = lane & 15, g = lane >> 4;
    const int gw    = blockIdx.x * 4 + w;
    const int strip = gw >> 3;
    const int chunk = gw & 7;
    const int b     = strip >> 8;
    const int q0    = (strip & 255) * 16;
    const int sBase = chunk * 512;
    const float SSC = 0.18033688011112042f;   // (1/8) * log2(e)

    const u16* qrow = qb + (size_t)((b << 12) + q0 + c) * 64 + g * 8;
    const bf16x8 qf0 = ld8(qrow);
    const bf16x8 qf1 = ld8(qrow + 32);

    const u16* kfp = kb  + (((size_t)b << 12) + sBase + c) * 64 + g * 8;
    const u16* vfp = vtb + (size_t)(b * 64 + c) * 4096 + sBase + g * 8;

    const u64* bp = bits + (size_t)((b << 12) + q0 + c) * 64 + chunk * 8;
    const u64 Wd0 = bp[0], Wd1 = bp[1], Wd2 = bp[2], Wd3 = bp[3];
    const u64 Wd4 = bp[4], Wd5 = bp[5], Wd6 = bp[6], Wd7 = bp[7];

    f32x4 acc0 = {}, acc1 = {}, acc2 = {}, acc3 = {};
    const f32x4 zf = {};
    float m_run = -__builtin_inff(), l_run = 0.f;

    bf16x8 k00 = ld8(kfp),            k01 = ld8(kfp + 32);
    bf16x8 k10 = ld8(kfp + 16 * 64),  k11 = ld8(kfp + 16 * 64 + 32);

    #pragma unroll
    for (int half = 0; half < 2; ++half) {
        const u64 Wr0 = half ? Wd4 : Wd0;
        const u64 Wr1 = half ? Wd5 : Wd1;
        const u64 Wr2 = half ? Wd6 : Wd2;
        const u64 Wr3 = half ? Wd7 : Wd3;
        #pragma unroll 1
        for (int it2 = 0; it2 < 8; ++it2) {
            const int it = half * 8 + it2;

            const u16* vp = vfp + it * 32;
            const bf16x8 v0 = ld8(vp);
            const bf16x8 v1 = ld8(vp + 16 * 4096);
            const bf16x8 v2 = ld8(vp + 32 * 4096);
            const bf16x8 v3 = ld8(vp + 48 * 4096);

            f32x4 d0 = MFMA16(k00, qf0, zf);
            d0 = MFMA16(k01, qf1, d0);
            f32x4 d1 = MFMA16(k10, qf0, zf);
            d1 = MFMA16(k11, qf1, d1);

            const int no = (it < 15) ? (it + 1) * 2048 : it * 2048;
            k00 = ld8(kfp + no);            k01 = ld8(kfp + no + 32);
            k10 = ld8(kfp + no + 16 * 64);  k11 = ld8(kfp + no + 16 * 64 + 32);

            const int sh = it2 * 8 + g;
            const unsigned t0 = (unsigned)(Wr0 >> sh);
            const unsigned t1 = (unsigned)(Wr1 >> sh);
            const unsigned t2 = (unsigned)(Wr2 >> sh);
            const unsigned t3 = (unsigned)(Wr3 >> sh);

            const float x0 = (t0 & 1u)  ? d0[0] * SSC : -1e9f;
            const float x1 = (t1 & 1u)  ? d0[1] * SSC : -1e9f;
            const float x2 = (t2 & 1u)  ? d0[2] * SSC : -1e9f;
            const float x3 = (t3 & 1u)  ? d0[3] * SSC : -1e9f;
            const float x4 = (t0 & 16u) ? d1[0] * SSC : -1e9f;
            const float x5 = (t1 & 16u) ? d1[1] * SSC : -1e9f;
            const float x6 = (t2 & 16u) ? d1[2] * SSC : -1e9f;
            const float x7 = (t3 & 16u) ? d1[3] * SSC : -1e9f;

            float tm = fmaxf(fmaxf(fmaxf(x0, x1), fmaxf(x2, x3)),
                             fmaxf(fmaxf(x4, x5), fmaxf(x6, x7)));
            tm = fmaxf(tm, __shfl_xor(tm, 16));
            tm = fmaxf(tm, __shfl_xor(tm, 32));
            const float m_new = fmaxf(m_run, tm);
            const float f = exp2f(m_run - m_new);

            const float p0 = exp2f(x0 - m_new), p1 = exp2f(x1 - m_new);
            const float p2 = exp2f(x2 - m_new), p3 = exp2f(x3 - m_new);
            const float p4 = exp2f(x4 - m_new), p5 = exp2f(x5 - m_new);
            const float p6 = exp2f(x6 - m_new), p7 = exp2f(x7 - m_new);
            float rs = ((p0 + p1) + (p2 + p3)) + ((p4 + p5) + (p6 + p7));
            rs += __shfl_xor(rs, 16);
            rs += __shfl_xor(rs, 32);
            l_run = l_run * f + rs;
            m_run = m_new;

            plds[w][c * 8 + ( g      ^ (c & 7))] = make_uint2(pk2(p0, p1), pk2(p2, p3));
            plds[w][c * 8 + ((g + 4) ^ (c & 7))] = make_uint2(pk2(p4, p5), pk2(p6, p7));

            if (__any(f < 1.0f)) {
                const float f0 = __shfl(f, g * 4 + 0);
                const float f1 = __shfl(f, g * 4 + 1);
                const float f2 = __shfl(f, g * 4 + 2);
                const float f3 = __shfl(f, g * 4 + 3);
                acc0[0] *= f0; acc0[1] *= f1; acc0[2] *= f2; acc0[3] *= f3;
                acc1[0] *= f0; acc1[1] *= f1; acc1[2] *= f2; acc1[3] *= f3;
                acc2[0] *= f0; acc2[1] *= f1; acc2[2] *= f2; acc2[3] *= f3;
                acc3[0] *= f0; acc3[1] *= f1; acc3[2] *= f2; acc3[3] *= f3;
            }

            union { uint2 u[2]; bf16x8 v; } pa;
            pa.u[0] = plds[w][c * 8 + ((2 * g    ) ^ (c & 7))];
            pa.u[1] = plds[w][c * 8 + ((2 * g + 1) ^ (c & 7))];

            acc0 = MFMA16(pa.v, v0, acc0);
            acc1 = MFMA16(pa.v, v1, acc1);
            acc2 = MFMA16(pa.v, v2, acc2);
            acc3 = MFMA16(pa.v, v3, acc3);
        }
    }

    const size_t pidx = (size_t)(strip * 8 + chunk) * 16;
    #pragma unroll
    for (int r = 0; r < 4; ++r) {
        const size_t row = pidx + g * 4 + r;
        pacc[row * 64 +  0 + c] = acc0[r];
        pacc[row * 64 + 16 + c] = acc1[r];
        pacc[row * 64 + 32 + c] = acc2[r];
        pacc[row * 64 + 48 + c] = acc3[r];
    }
    if (lane < 16) {
        pm[pidx + c] = m_run;
        pl[pidx + c] = l_run;
    }
}

// ---------------- Kernel 3: combine 8 s-chunk partials per row ----------------
__global__ __launch_bounds__(256) void comb_kernel(
    const float* __restrict__ pacc, const float* __restrict__ pm,
    const float* __restrict__ pl, float* __restrict__ out)
{
    const int t = blockIdx.x * 256 + threadIdx.x;
    const int r = t >> 6, dv = t & 63;
    const int strip = r >> 4, qi = r & 15;
    const int base = strip * 128 + qi;
    float mv[8];
    float M = -__builtin_inff();
    #pragma unroll
    for (int cc = 0; cc < 8; ++cc) { mv[cc] = pm[base + cc * 16]; M = fmaxf(M, mv[cc]); }
    float num = 0.f, den = 0.f;
    #pragma unroll
    for (int cc = 0; cc < 8; ++cc) {
        const float wgt = exp2f(mv[cc] - M);
        num += wgt * pacc[(size_t)(base + cc * 16) * 64 + dv];
        den += wgt * pl[base + cc * 16];
    }
    out[t] = num / den;
}

extern "C" void kernel_launch(void* const* d_in, const int* in_sizes, int n_in,
                              void* d_out, int out_size, void* d_ws, size_t ws_size,
                              hipStream_t stream)
{
    const float* Q    = (const float*)d_in[0];
    const float* K    = (const float*)d_in[1];
    const float* V    = (const float*)d_in[2];
    const int*   mask = (const int*)d_in[3];
    const float* Wq   = (const float*)d_in[4];
    const float* bq   = (const float*)d_in[5];
    const float* Wk   = (const float*)d_in[6];
    const float* bk   = (const float*)d_in[7];
    const float* Wv   = (const float*)d_in[8];
    const float* bv   = (const float*)d_in[9];
    float* out = (float*)d_out;

    char* ws = (char*)d_ws;
    u16*   wb   = (u16*)(ws);                            // 384 KB
    u16*   qb   = (u16*)(ws + 393216);                   // 1 MB
    u16*   kb   = (u16*)(ws + 393216 + 1048576);         // 1 MB
    u16*   vtb  = (u16*)(ws + 393216 + 2097152);         // 1 MB
    u64*   bits = (u64*)(ws + 4194304);                  // 4 MB: [8192][16][4] u64
    float* pm   = (float*)(ws + 8388608);                // 256 KB
    float* pl   = (float*)(ws + 8388608 + 262144);       // 256 KB
    float* pacc = (float*)(ws + 8388608 + 524288);       // 16 MB

    wcvt_kernel<<<96, 256, 0, stream>>>(Wq, Wk, Wv, wb);
    fused_kernel<<<4480, 256, 0, stream>>>(Q, K, V, bq, bk, bv, wb, mask,
                                           qb, kb, vtb, bits);
    attn_kernel<<<1024, 256, 0, stream>>>(bits, qb, kb, vtb, pacc, pm, pl);
    comb_kernel<<<2048, 256, 0, stream>>>(pacc, pm, pl, out);
}